// Round 3
// baseline (358.348 us; speedup 1.0000x reference)
//
#include <hip/hip_runtime.h>
#include <hip/hip_bf16.h>

#define NEG_INF_F (-4294967295.0f)  // -(2^32)+1, matches reference padding

typedef __attribute__((ext_vector_type(8))) short bf16x8;   // MFMA A/B frag (4 VGPRs)
typedef __attribute__((ext_vector_type(4))) float f32x4;    // MFMA C/D frag

__device__ __forceinline__ unsigned short f2bf(float x) {
    unsigned u = __float_as_uint(x);
    return (unsigned short)((u + 0x7fffu + ((u >> 16) & 1u)) >> 16);  // RNE
}
__device__ __forceinline__ unsigned f2bf2(float a, float b) {
    __hip_bfloat162 h2 = __float22bfloat162_rn(make_float2(a, b));
    unsigned r; __builtin_memcpy(&r, &h2, 4); return r;
}
union FragU { unsigned u[4]; bf16x8 h; };

// One-pass design: K streamed HBM->regs once; online softmax fuses pool into
// the score loop. LDS ~28 KB; VGPR capped at 128 -> 4 blocks/CU, 16 waves/CU.
struct __align__(16) Smem {
    unsigned short Mt[64 * 128];    // 16384 B  M^T bf16 [n][k], swizzle g=(k>>3)^(n&15)
    unsigned short h1s[4][16 * 64]; //  8192 B  per-wave h1 C->A scratch
    float q[128];                   //   512 B
    float cpart[256];               //  1024 B  4 partial chunks of c[n]
    float Om[4][128];               //  2048 B  per-wave pooled partials
    float mw[4], lw[4];             //    32 B  per-wave online-softmax state
};

// 2nd __launch_bounds__ arg = min BLOCKS/CU on this toolchain (R3 evidence):
// (256,4) -> 16 waves/CU -> VGPR cap 128. R1 post-mortem: kernel is
// latency-bound (MfmaUtil 2.4%, VALUBusy 16%, HBM 18%, occ 29%) -> buy waves.
__global__ __launch_bounds__(256, 4)
void attn_fused(const float* __restrict__ Q,    // [2048,128]
                const float* __restrict__ Kg,   // [2048,200,128]
                const int*   __restrict__ kid,  // [2048,200]
                const float* __restrict__ W1,   // [512,64]
                const float* __restrict__ b1,   // [64]
                const float* __restrict__ W2,   // [64,32]
                const float* __restrict__ b2,   // [32]
                const float* __restrict__ W3,   // [32,1]
                const float* __restrict__ b3,   // [1]
                float* __restrict__ out)        // [2048,128]
{
    __shared__ Smem sm;
    const int b    = blockIdx.x;
    const int tid  = threadIdx.x;
    const int wave = tid >> 6;
    const int lane = tid & 63;
    const int l15  = lane & 15;
    const int quad = lane >> 4;

    if (tid < 128) sm.q[tid] = Q[b * 128 + tid];

    // W2 B-frags + layer-3 consts (global L2-hot, no LDS dependency)
    bf16x8 W2f[2][2];
    #pragma unroll
    for (int ks = 0; ks < 2; ++ks) {
        #pragma unroll
        for (int nt = 0; nt < 2; ++nt) {
            const int n = nt * 16 + l15;
            const int kb = ks * 32 + quad * 8;
            bf16x8 f;
            #pragma unroll
            for (int j = 0; j < 8; ++j) f[j] = (short)f2bf(W2[(kb + j) * 32 + n]);
            W2f[ks][nt] = f;
        }
    }
    const float w3a = W3[l15],  w3b = W3[16 + l15];
    const float b2a = b2[l15],  b2b = b2[16 + l15];
    const float b3v = b3[0];
    __syncthreads();

    // ---- cooperative M build: M[k][n] = (W1k-W1d)[k][n] + q[k]*W1p[k][n] ----
    // stored transposed Mt[n][k], bf16, granule swizzle g=(k>>3)^(n&15).
    {
        const int n  = tid & 63;
        const int ko = (tid >> 6) * 2;
        #pragma unroll
        for (int i = 0; i < 16; ++i) {
            const int k = i * 8 + ko;
            const float v0 = (W1[(128 + k) * 64 + n] - W1[(256 + k) * 64 + n])
                           + sm.q[k] * W1[(384 + k) * 64 + n];
            const float v1 = (W1[(129 + k) * 64 + n] - W1[(257 + k) * 64 + n])
                           + sm.q[k + 1] * W1[(385 + k) * 64 + n];
            const int g = (k >> 3) ^ (n & 15);
            *reinterpret_cast<unsigned*>(&sm.Mt[n * 128 + g * 8 + (k & 7)]) = f2bf2(v0, v1);
        }
    }
    // c[n] partials: wave w does 32 k's
    {
        const int n = tid & 63, kc = tid >> 6;
        float acc = (kc == 0) ? b1[n] : 0.0f;
        #pragma unroll 4
        for (int i = 0; i < 32; ++i) {
            const int k = kc * 32 + i;
            acc += sm.q[k] * (W1[k * 64 + n] + W1[(256 + k) * 64 + n]);
        }
        sm.cpart[kc * 64 + n] = acc;
    }
    __syncthreads();

    float cn[4];
    #pragma unroll
    for (int nt = 0; nt < 4; ++nt) {
        const int n = nt * 16 + l15;
        cn[nt] = sm.cpart[n] + sm.cpart[64 + n] + sm.cpart[128 + n] + sm.cpart[192 + n];
    }

    const float* kbase = Kg + (size_t)b * 25600;
    unsigned short* h1w = &sm.h1s[wave][0];
    const f32x4 zero4 = {0.f, 0.f, 0.f, 0.f};

    float O[32];
    #pragma unroll
    for (int i = 0; i < 32; ++i) O[i] = 0.0f;
    float mrun = -__builtin_inff(), lrun = 0.0f;

    // ---- tile loop: wave w does tiles w, w+4, w+8 (w==0 also 12) ----
    for (int tile = wave; tile < 13; tile += 4) {
        const int t0 = tile * 16;
        const int t  = t0 + l15;
        const int tr = min(t, 199);               // clamp OOB rows (tile 12)
        const float* kr = kbase + tr * 128;
        float4 ka[4], kb_[4];
        #pragma unroll
        for (int ks = 0; ks < 4; ++ks) {
            ka[ks]  = *reinterpret_cast<const float4*>(kr + ks * 32 + quad * 8);
            kb_[ks] = *reinterpret_cast<const float4*>(kr + ks * 32 + quad * 8 + 4);
        }
        const int kidv = kid[b * 200 + tr];

        f32x4 acc[4] = {zero4, zero4, zero4, zero4};
        #pragma unroll
        for (int ks = 0; ks < 4; ++ks) {
            FragU A;
            A.u[0] = f2bf2(ka[ks].x,  ka[ks].y);
            A.u[1] = f2bf2(ka[ks].z,  ka[ks].w);
            A.u[2] = f2bf2(kb_[ks].x, kb_[ks].y);
            A.u[3] = f2bf2(kb_[ks].z, kb_[ks].w);
            #pragma unroll
            for (int nt = 0; nt < 4; ++nt) {
                const int n = nt * 16 + l15;
                const int g = (ks * 4 + quad) ^ l15;
                const bf16x8 Bf = *reinterpret_cast<const bf16x8*>(&sm.Mt[n * 128 + g * 8]);
                acc[nt] = __builtin_amdgcn_mfma_f32_16x16x32_bf16(A.h, Bf, acc[nt], 0, 0, 0);
            }
        }
        // epilogue: + c[n], relu, paired cvt_pk bf16 -> wave-private scratch
        // in A-layout (verified correct in R1: same indices as scalar form).
        {
            const int m0 = quad * 4;
            #pragma unroll
            for (int nt = 0; nt < 4; ++nt) {
                const int n = nt * 16 + l15;
                const float h0 = fmaxf(acc[nt][0] + cn[nt], 0.0f);
                const float h1 = fmaxf(acc[nt][1] + cn[nt], 0.0f);
                const float h2 = fmaxf(acc[nt][2] + cn[nt], 0.0f);
                const float h3 = fmaxf(acc[nt][3] + cn[nt], 0.0f);
                const unsigned p01 = f2bf2(h0, h1);
                const unsigned p23 = f2bf2(h2, h3);
                const int nhi = n >> 3, nlo = n & 7;
                h1w[(m0+0)*64 + ((nhi ^ ((m0+0)&7))*8) + nlo] = (unsigned short)(p01);
                h1w[(m0+1)*64 + ((nhi ^ ((m0+1)&7))*8) + nlo] = (unsigned short)(p01 >> 16);
                h1w[(m0+2)*64 + ((nhi ^ ((m0+2)&7))*8) + nlo] = (unsigned short)(p23);
                h1w[(m0+3)*64 + ((nhi ^ ((m0+3)&7))*8) + nlo] = (unsigned short)(p23 >> 16);
            }
        }
        // layer 2: [16,64] @ [64,32]
        f32x4 p0 = zero4, p1 = zero4;
        #pragma unroll
        for (int ks = 0; ks < 2; ++ks) {
            const int g = (ks * 4 + quad) ^ (l15 & 7);
            const bf16x8 A2l = *reinterpret_cast<const bf16x8*>(&h1w[l15 * 64 + g * 8]);
            p0 = __builtin_amdgcn_mfma_f32_16x16x32_bf16(A2l, W2f[ks][0], p0, 0, 0, 0);
            p1 = __builtin_amdgcn_mfma_f32_16x16x32_bf16(A2l, W2f[ks][1], p1, 0, 0, 0);
        }
        // layer 3: relu + dot(W3), reduce over the 16 cols (l15)
        float sv[4];
        #pragma unroll
        for (int r = 0; r < 4; ++r)
            sv[r] = fmaxf(p0[r] + b2a, 0.f) * w3a + fmaxf(p1[r] + b2b, 0.f) * w3b;
        #pragma unroll
        for (int off = 1; off < 16; off <<= 1) {
            #pragma unroll
            for (int r = 0; r < 4; ++r) sv[r] += __shfl_xor(sv[r], off);
        }
        // broadcast: this lane needs score of t0+l15 (lives in quad l15>>2, reg l15&3)
        const int src = (l15 >> 2) * 16;
        const float s0 = __shfl(sv[0], src), s1 = __shfl(sv[1], src);
        const float s2 = __shfl(sv[2], src), s3 = __shfl(sv[3], src);
        const int rr = l15 & 3;
        const float sres = (rr == 0) ? s0 : (rr == 1) ? s1 : (rr == 2) ? s2 : s3;
        float x;
        if (t < 200) x = (kidv != 0) ? (sres + b3v) : NEG_INF_F;
        else         x = -__builtin_inff();
        // online softmax update (all cross-lane ops within 16-lane groups)
        float tmax = x;
        #pragma unroll
        for (int off = 1; off < 16; off <<= 1) tmax = fmaxf(tmax, __shfl_xor(tmax, off));
        const float mnew  = fmaxf(mrun, tmax);
        const float alpha = __expf(mrun - mnew);
        const float w     = __expf(x - mnew);
        float tsum = w;
        #pragma unroll
        for (int off = 1; off < 16; off <<= 1) tsum += __shfl_xor(tsum, off);
        lrun = lrun * alpha + tsum;
        mrun = mnew;
        #pragma unroll
        for (int ks = 0; ks < 4; ++ks) {
            O[ks*8+0] = fmaf(O[ks*8+0], alpha, w * ka[ks].x);
            O[ks*8+1] = fmaf(O[ks*8+1], alpha, w * ka[ks].y);
            O[ks*8+2] = fmaf(O[ks*8+2], alpha, w * ka[ks].z);
            O[ks*8+3] = fmaf(O[ks*8+3], alpha, w * ka[ks].w);
            O[ks*8+4] = fmaf(O[ks*8+4], alpha, w * kb_[ks].x);
            O[ks*8+5] = fmaf(O[ks*8+5], alpha, w * kb_[ks].y);
            O[ks*8+6] = fmaf(O[ks*8+6], alpha, w * kb_[ks].z);
            O[ks*8+7] = fmaf(O[ks*8+7], alpha, w * kb_[ks].w);
        }
    }

    // intra-wave reduce of O over l15 (each quad owns cols quad*8+ks*32..+7)
    #pragma unroll
    for (int off = 1; off < 16; off <<= 1) {
        #pragma unroll
        for (int i = 0; i < 32; ++i) O[i] += __shfl_xor(O[i], off);
    }
    if (l15 == 0) {
        #pragma unroll
        for (int ks = 0; ks < 4; ++ks) {
            *reinterpret_cast<float4*>(&sm.Om[wave][ks * 32 + quad * 8]) =
                make_float4(O[ks*8+0], O[ks*8+1], O[ks*8+2], O[ks*8+3]);
            *reinterpret_cast<float4*>(&sm.Om[wave][ks * 32 + quad * 8 + 4]) =
                make_float4(O[ks*8+4], O[ks*8+5], O[ks*8+6], O[ks*8+7]);
        }
    }
    if (lane == 0) { sm.mw[wave] = mrun; sm.lw[wave] = lrun; }
    __syncthreads();

    // ---- merge 4 waves' online states, normalize, store ----
    if (tid < 128) {
        const float M = fmaxf(fmaxf(sm.mw[0], sm.mw[1]), fmaxf(sm.mw[2], sm.mw[3]));
        float den = 0.f, val = 0.f;
        #pragma unroll
        for (int w = 0; w < 4; ++w) {
            const float a = __expf(sm.mw[w] - M);
            den += sm.lw[w] * a;
            val += sm.Om[w][tid] * a;
        }
        out[(size_t)b * 128 + tid] = val / (den * 200.0f);  // softmax norm + mean(/T)
    }
}

extern "C" void kernel_launch(void* const* d_in, const int* in_sizes, int n_in,
                              void* d_out, int out_size, void* d_ws, size_t ws_size,
                              hipStream_t stream) {
    (void)in_sizes; (void)n_in; (void)out_size; (void)d_ws; (void)ws_size;
    attn_fused<<<dim3(2048), dim3(256), 0, stream>>>(
        (const float*)d_in[0], (const float*)d_in[1], (const int*)d_in[2],
        (const float*)d_in[3], (const float*)d_in[4], (const float*)d_in[5],
        (const float*)d_in[6], (const float*)d_in[7], (const float*)d_in[8],
        (float*)d_out);
}

// Round 7
// 321.913 us; speedup vs baseline: 1.1132x; 1.1132x over previous
//
#include <hip/hip_runtime.h>
#include <hip/hip_bf16.h>

#define NEG_INF_F (-4294967295.0f)  // -(2^32)+1, matches reference padding

typedef __attribute__((ext_vector_type(8))) short bf16x8;   // MFMA A/B frag (4 VGPRs)
typedef __attribute__((ext_vector_type(4))) float f32x4;    // MFMA C/D frag

__device__ __forceinline__ unsigned short f2bf(float x) {
    unsigned u = __float_as_uint(x);
    return (unsigned short)((u + 0x7fffu + ((u >> 16) & 1u)) >> 16);  // RNE
}
__device__ __forceinline__ unsigned f2bf2(float a, float b) {
    __hip_bfloat162 h2 = __float22bfloat162_rn(make_float2(a, b));
    unsigned r; __builtin_memcpy(&r, &h2, 4); return r;
}
union FragU { unsigned u[4]; bf16x8 h; };

// One-pass design: K streamed HBM->regs once; online softmax fuses pool into
// the score loop. LDS ~28 KB.
// R5 post-mortem: vectorized prologue (R4/R5) caused elevated absmax and a
// post-timing divergence that could not be root-caused -> dropped permanently.
// This version = R0 prologue/tile-loop (proven pre+post) + paired-cvt epilogue
// (proven bit-equivalent in R1/R3, absmax 1.525879e-05) + s_setprio around the
// MFMA clusters (zero numerics risk) + 1-shfl score broadcast (same bits).
struct __align__(16) Smem {
    unsigned short Mt[64 * 128];    // 16384 B  M^T bf16 [n][k], swizzle g=(k>>3)^(n&15)
    unsigned short h1s[4][16 * 64]; //  8192 B  per-wave h1 C->A scratch
    float q[128];                   //   512 B
    float cpart[256];               //  1024 B  4 k-chunk partials of c[n]
    float Om[4][128];               //  2048 B  per-wave pooled partials
    float mw[4], lw[4];             //    32 B  per-wave online-softmax state
};

// 2nd __launch_bounds__ arg = min BLOCKS/CU on this toolchain:
// (256,3) -> 12 waves/CU -> VGPR cap 170; tile loop needs ~150-170 live
// (R1/R3 evidence: any lower cap spills the O accumulator, +65MB scratch).
__global__ __launch_bounds__(256, 3)
void attn_fused(const float* __restrict__ Q,    // [2048,128]
                const float* __restrict__ Kg,   // [2048,200,128]
                const int*   __restrict__ kid,  // [2048,200]
                const float* __restrict__ W1,   // [512,64]
                const float* __restrict__ b1,   // [64]
                const float* __restrict__ W2,   // [64,32]
                const float* __restrict__ b2,   // [32]
                const float* __restrict__ W3,   // [32,1]
                const float* __restrict__ b3,   // [1]
                float* __restrict__ out)        // [2048,128]
{
    __shared__ Smem sm;
    const int b    = blockIdx.x;
    const int tid  = threadIdx.x;
    const int wave = tid >> 6;
    const int lane = tid & 63;
    const int l15  = lane & 15;
    const int quad = lane >> 4;

    if (tid < 128) sm.q[tid] = Q[b * 128 + tid];

    // W2 B-frags + layer-3 consts (global L2-hot, no LDS dependency)
    bf16x8 W2f[2][2];
    #pragma unroll
    for (int ks = 0; ks < 2; ++ks) {
        #pragma unroll
        for (int nt = 0; nt < 2; ++nt) {
            const int n = nt * 16 + l15;
            const int kb = ks * 32 + quad * 8;
            bf16x8 f;
            #pragma unroll
            for (int j = 0; j < 8; ++j) f[j] = (short)f2bf(W2[(kb + j) * 32 + n]);
            W2f[ks][nt] = f;
        }
    }
    const float w3a = W3[l15],  w3b = W3[16 + l15];
    const float b2a = b2[l15],  b2b = b2[16 + l15];
    const float b3v = b3[0];
    __syncthreads();

    // ---- cooperative M build: M[k][n] = (W1k-W1d)[k][n] + q[k]*W1p[k][n] ----
    // stored transposed Mt[n][k], bf16, granule swizzle g=(k>>3)^(n&15).
    // EXACT R0 form (proven pre+post timing).
    {
        const int n  = tid & 63;
        const int ko = (tid >> 6) * 2;
        #pragma unroll
        for (int i = 0; i < 16; ++i) {
            const int k = i * 8 + ko;
            const float v0 = (W1[(128 + k) * 64 + n] - W1[(256 + k) * 64 + n])
                           + sm.q[k] * W1[(384 + k) * 64 + n];
            const float v1 = (W1[(129 + k) * 64 + n] - W1[(257 + k) * 64 + n])
                           + sm.q[k + 1] * W1[(385 + k) * 64 + n];
            const int g = (k >> 3) ^ (n & 15);
            *reinterpret_cast<unsigned*>(&sm.Mt[n * 128 + g * 8 + (k & 7)]) = f2bf2(v0, v1);
        }
    }
    // c[n] partials: wave w does 32 k's. EXACT R0 form.
    {
        const int n = tid & 63, kc = tid >> 6;
        float acc = (kc == 0) ? b1[n] : 0.0f;
        #pragma unroll 4
        for (int i = 0; i < 32; ++i) {
            const int k = kc * 32 + i;
            acc += sm.q[k] * (W1[k * 64 + n] + W1[(256 + k) * 64 + n]);
        }
        sm.cpart[kc * 64 + n] = acc;
    }
    __syncthreads();

    float cn[4];
    #pragma unroll
    for (int nt = 0; nt < 4; ++nt) {
        const int n = nt * 16 + l15;
        cn[nt] = sm.cpart[n] + sm.cpart[64 + n] + sm.cpart[128 + n] + sm.cpart[192 + n];
    }

    const float* kbase = Kg + (size_t)b * 25600;
    unsigned short* h1w = &sm.h1s[wave][0];
    const f32x4 zero4 = {0.f, 0.f, 0.f, 0.f};

    float O[32];
    #pragma unroll
    for (int i = 0; i < 32; ++i) O[i] = 0.0f;
    float mrun = -__builtin_inff(), lrun = 0.0f;

    // ---- tile loop: wave w does tiles w, w+4, w+8 (w==0 also 12) ----
    for (int tile = wave; tile < 13; tile += 4) {
        const int t0 = tile * 16;
        const int t  = t0 + l15;
        const int tr = min(t, 199);               // clamp OOB rows (tile 12)
        const float* kr = kbase + tr * 128;
        float4 ka[4], kb_[4];
        #pragma unroll
        for (int ks = 0; ks < 4; ++ks) {
            ka[ks]  = *reinterpret_cast<const float4*>(kr + ks * 32 + quad * 8);
            kb_[ks] = *reinterpret_cast<const float4*>(kr + ks * 32 + quad * 8 + 4);
        }
        const int kidv = kid[b * 200 + tr];

        f32x4 acc[4] = {zero4, zero4, zero4, zero4};
        // T5: favor this wave while it feeds the matrix pipe (waves are
        // phase-staggered across tiles -> scheduler has roles to arbitrate).
        __builtin_amdgcn_s_setprio(1);
        #pragma unroll
        for (int ks = 0; ks < 4; ++ks) {
            FragU A;
            A.u[0] = f2bf2(ka[ks].x,  ka[ks].y);
            A.u[1] = f2bf2(ka[ks].z,  ka[ks].w);
            A.u[2] = f2bf2(kb_[ks].x, kb_[ks].y);
            A.u[3] = f2bf2(kb_[ks].z, kb_[ks].w);
            #pragma unroll
            for (int nt = 0; nt < 4; ++nt) {
                const int n = nt * 16 + l15;
                const int g = (ks * 4 + quad) ^ l15;
                const bf16x8 Bf = *reinterpret_cast<const bf16x8*>(&sm.Mt[n * 128 + g * 8]);
                acc[nt] = __builtin_amdgcn_mfma_f32_16x16x32_bf16(A.h, Bf, acc[nt], 0, 0, 0);
            }
        }
        __builtin_amdgcn_s_setprio(0);
        // epilogue: + c[n], relu, paired cvt_pk bf16 -> wave-private scratch
        // in A-layout (proven bit-equivalent in R1/R3: absmax 1.525879e-05).
        {
            const int m0 = quad * 4;
            #pragma unroll
            for (int nt = 0; nt < 4; ++nt) {
                const int n = nt * 16 + l15;
                const float h0 = fmaxf(acc[nt][0] + cn[nt], 0.0f);
                const float h1 = fmaxf(acc[nt][1] + cn[nt], 0.0f);
                const float h2 = fmaxf(acc[nt][2] + cn[nt], 0.0f);
                const float h3 = fmaxf(acc[nt][3] + cn[nt], 0.0f);
                const unsigned p01 = f2bf2(h0, h1);
                const unsigned p23 = f2bf2(h2, h3);
                const int nhi = n >> 3, nlo = n & 7;
                h1w[(m0+0)*64 + ((nhi ^ ((m0+0)&7))*8) + nlo] = (unsigned short)(p01);
                h1w[(m0+1)*64 + ((nhi ^ ((m0+1)&7))*8) + nlo] = (unsigned short)(p01 >> 16);
                h1w[(m0+2)*64 + ((nhi ^ ((m0+2)&7))*8) + nlo] = (unsigned short)(p23);
                h1w[(m0+3)*64 + ((nhi ^ ((m0+3)&7))*8) + nlo] = (unsigned short)(p23 >> 16);
            }
        }
        // layer 2: [16,64] @ [64,32]
        f32x4 p0 = zero4, p1 = zero4;
        __builtin_amdgcn_s_setprio(1);
        #pragma unroll
        for (int ks = 0; ks < 2; ++ks) {
            const int g = (ks * 4 + quad) ^ (l15 & 7);
            const bf16x8 A2l = *reinterpret_cast<const bf16x8*>(&h1w[l15 * 64 + g * 8]);
            p0 = __builtin_amdgcn_mfma_f32_16x16x32_bf16(A2l, W2f[ks][0], p0, 0, 0, 0);
            p1 = __builtin_amdgcn_mfma_f32_16x16x32_bf16(A2l, W2f[ks][1], p1, 0, 0, 0);
        }
        __builtin_amdgcn_s_setprio(0);
        // layer 3: relu + dot(W3), reduce over the 16 cols (l15)
        float sv[4];
        #pragma unroll
        for (int r = 0; r < 4; ++r)
            sv[r] = fmaxf(p0[r] + b2a, 0.f) * w3a + fmaxf(p1[r] + b2b, 0.f) * w3b;
        #pragma unroll
        for (int off = 1; off < 16; off <<= 1) {
            #pragma unroll
            for (int r = 0; r < 4; ++r) sv[r] += __shfl_xor(sv[r], off);
        }
        // broadcast: lane needs score of row l15 (held by quad l15>>2, reg l15&3).
        // Select-then-shuffle: source lane (l15>>2)*16 + (l15&3) has, after the
        // local select on ITS l15&3 (= our l15&3), exactly sv[l15&3] of the
        // right quad. Same bits as the 4-shfl form, 3 fewer cross-lane hops.
        const int rr = l15 & 3;
        const float svx = (rr == 0) ? sv[0] : (rr == 1) ? sv[1] : (rr == 2) ? sv[2] : sv[3];
        const float sres = __shfl(svx, (l15 >> 2) * 16 + rr);
        float x;
        if (t < 200) x = (kidv != 0) ? (sres + b3v) : NEG_INF_F;
        else         x = -__builtin_inff();
        // online softmax update (all cross-lane ops within 16-lane groups)
        float tmax = x;
        #pragma unroll
        for (int off = 1; off < 16; off <<= 1) tmax = fmaxf(tmax, __shfl_xor(tmax, off));
        const float mnew  = fmaxf(mrun, tmax);
        const float alpha = __expf(mrun - mnew);
        const float w     = __expf(x - mnew);
        float tsum = w;
        #pragma unroll
        for (int off = 1; off < 16; off <<= 1) tsum += __shfl_xor(tsum, off);
        lrun = lrun * alpha + tsum;
        mrun = mnew;
        #pragma unroll
        for (int ks = 0; ks < 4; ++ks) {
            O[ks*8+0] = fmaf(O[ks*8+0], alpha, w * ka[ks].x);
            O[ks*8+1] = fmaf(O[ks*8+1], alpha, w * ka[ks].y);
            O[ks*8+2] = fmaf(O[ks*8+2], alpha, w * ka[ks].z);
            O[ks*8+3] = fmaf(O[ks*8+3], alpha, w * ka[ks].w);
            O[ks*8+4] = fmaf(O[ks*8+4], alpha, w * kb_[ks].x);
            O[ks*8+5] = fmaf(O[ks*8+5], alpha, w * kb_[ks].y);
            O[ks*8+6] = fmaf(O[ks*8+6], alpha, w * kb_[ks].z);
            O[ks*8+7] = fmaf(O[ks*8+7], alpha, w * kb_[ks].w);
        }
    }

    // intra-wave reduce of O over l15 (each quad owns cols quad*8+ks*32..+7)
    #pragma unroll
    for (int off = 1; off < 16; off <<= 1) {
        #pragma unroll
        for (int i = 0; i < 32; ++i) O[i] += __shfl_xor(O[i], off);
    }
    if (l15 == 0) {
        #pragma unroll
        for (int ks = 0; ks < 4; ++ks) {
            *reinterpret_cast<float4*>(&sm.Om[wave][ks * 32 + quad * 8]) =
                make_float4(O[ks*8+0], O[ks*8+1], O[ks*8+2], O[ks*8+3]);
            *reinterpret_cast<float4*>(&sm.Om[wave][ks * 32 + quad * 8 + 4]) =
                make_float4(O[ks*8+4], O[ks*8+5], O[ks*8+6], O[ks*8+7]);
        }
    }
    if (lane == 0) { sm.mw[wave] = mrun; sm.lw[wave] = lrun; }
    __syncthreads();

    // ---- merge 4 waves' online states, normalize, store ----
    if (tid < 128) {
        const float M = fmaxf(fmaxf(sm.mw[0], sm.mw[1]), fmaxf(sm.mw[2], sm.mw[3]));
        float den = 0.f, val = 0.f;
        #pragma unroll
        for (int w = 0; w < 4; ++w) {
            const float a = __expf(sm.mw[w] - M);
            den += sm.lw[w] * a;
            val += sm.Om[w][tid] * a;
        }
        out[(size_t)b * 128 + tid] = val / (den * 200.0f);  // softmax norm + mean(/T)
    }
}

extern "C" void kernel_launch(void* const* d_in, const int* in_sizes, int n_in,
                              void* d_out, int out_size, void* d_ws, size_t ws_size,
                              hipStream_t stream) {
    (void)in_sizes; (void)n_in; (void)out_size; (void)d_ws; (void)ws_size;
    attn_fused<<<dim3(2048), dim3(256), 0, stream>>>(
        (const float*)d_in[0], (const float*)d_in[1], (const int*)d_in[2],
        (const float*)d_in[3], (const float*)d_in[4], (const float*)d_in[5],
        (const float*)d_in[6], (const float*)d_in[7], (const float*)d_in[8],
        (float*)d_out);
}